// Round 1
// baseline (1971.197 us; speedup 1.0000x reference)
//
#include <hip/hip_runtime.h>
#include <hip/hip_bf16.h>
#include <cstddef>

#define E_EDGES 1000000
#define N_ATOMS_C 100000
#define NC 256
#define EPS_C 1e-5f
#define INV_SQRT2 0.7071067811865476f

// ---------- bf16 helpers (raw ushort, RNE) ----------
__device__ __forceinline__ unsigned short f2bf(float x) {
    unsigned int u = __float_as_uint(x);
    unsigned int r = (u + 0x7FFFu + ((u >> 16) & 1u)) >> 16;
    return (unsigned short)r;
}
__device__ __forceinline__ float bf2f(unsigned short s) {
    return __uint_as_float(((unsigned int)s) << 16);
}

// ---------- zero the stats region ----------
__global__ void k_zero(float* __restrict__ p, int n) {
    int i = blockIdx.x * 256 + threadIdx.x;
    if (i < n) p[i] = 0.f;
}

// ---------- per-crystal edge counts via binary search (cidx sorted) ----------
__device__ __forceinline__ int lowb(const int* __restrict__ c, int n, int key) {
    int lo = 0, hi = n;
    while (lo < hi) { int m = (lo + hi) >> 1; if (c[m] < key) lo = m + 1; else hi = m; }
    return lo;
}
__global__ void k_bounds(const int* __restrict__ cidx, float* __restrict__ cntb) {
    int cr = threadIdx.x;           // 0..255
    int a = lowb(cidx, E_EDGES, cr);
    int b = lowb(cidx, E_EDGES, cr + 1);
    cntb[cr] = (float)(b - a);
}

// ---------- K1: gated = [diff||edge] @ W_full, + per-crystal stats1 ----------
// grid: 15625 tiles * 2 f-halves. block 256. tile = 64 edges x 64 feats.
#define TE 64
#define SA 68   // As row stride (floats): (68*e)%32 = 4e -> consecutive-e lanes hit distinct banks
__global__ __launch_bounds__(256) void k_gemm1(
    const float* __restrict__ atom, const float* __restrict__ edg,
    const int* __restrict__ nbr, const int* __restrict__ cidx,
    const float* __restrict__ Wf,
    unsigned short* __restrict__ gated,
    float* __restrict__ sum1, float* __restrict__ sq1)
{
    __shared__ float Wl[128 * 64];      // W_full[k][half*64 + fl], 32 KB
    __shared__ float As[TE * SA];       // A tile (one 64-k phase at a time), 17 KB
    __shared__ int   cl[TE];
    __shared__ float ptS[4][64], ptQ[4][64];

    const int bid  = blockIdx.x;
    const int tile = bid >> 1, half = bid & 1;
    const int e0   = tile * TE;
    const int t    = threadIdx.x;

    // stage W half (coalesced float4)
    for (int idx = t; idx < 128 * 16; idx += 256) {
        int k = idx >> 4, q = idx & 15;
        *(float4*)(Wl + k * 64 + q * 4) =
            *(const float4*)(Wf + (size_t)k * 128 + half * 64 + q * 4);
    }
    if (t < TE) cl[t] = cidx[e0 + t];
    // stage phase0: diff = atom[i1] - atom[i0]
    for (int idx = t; idx < TE * 16; idx += 256) {
        int e = idx >> 4, q = idx & 15;
        int ge = e0 + e;
        int i0 = nbr[2 * ge], i1 = nbr[2 * ge + 1];
        float4 a1 = *(const float4*)(atom + (size_t)i1 * 64 + q * 4);
        float4 a0 = *(const float4*)(atom + (size_t)i0 * 64 + q * 4);
        float4 d; d.x = a1.x - a0.x; d.y = a1.y - a0.y; d.z = a1.z - a0.z; d.w = a1.w - a0.w;
        *(float4*)(As + e * SA + q * 4) = d;
    }
    __syncthreads();

    const int tx = t & 15, ty = t >> 4;     // f-group, e-group
    const int f0 = tx * 4;
    float acc[4][4];
    #pragma unroll
    for (int i = 0; i < 4; i++) { acc[i][0]=0.f; acc[i][1]=0.f; acc[i][2]=0.f; acc[i][3]=0.f; }

    // phase0 k-loop (k = 0..63), float4 k-blocking
    #pragma unroll 4
    for (int k4 = 0; k4 < 64; k4 += 4) {
        float4 a[4];
        #pragma unroll
        for (int i = 0; i < 4; i++) a[i] = *(float4*)(As + (ty + 16 * i) * SA + k4);
        #pragma unroll
        for (int kk = 0; kk < 4; kk++) {
            float4 b = *(float4*)(Wl + (k4 + kk) * 64 + f0);
            #pragma unroll
            for (int i = 0; i < 4; i++) {
                float av = (&a[i].x)[kk];
                acc[i][0] = fmaf(av, b.x, acc[i][0]);
                acc[i][1] = fmaf(av, b.y, acc[i][1]);
                acc[i][2] = fmaf(av, b.z, acc[i][2]);
                acc[i][3] = fmaf(av, b.w, acc[i][3]);
            }
        }
    }
    __syncthreads();
    // stage phase1: edge features
    for (int idx = t; idx < TE * 16; idx += 256) {
        int e = idx >> 4, q = idx & 15;
        *(float4*)(As + e * SA + q * 4) =
            *(const float4*)(edg + (size_t)(e0 + e) * 64 + q * 4);
    }
    __syncthreads();
    #pragma unroll 4
    for (int k4 = 0; k4 < 64; k4 += 4) {
        float4 a[4];
        #pragma unroll
        for (int i = 0; i < 4; i++) a[i] = *(float4*)(As + (ty + 16 * i) * SA + k4);
        #pragma unroll
        for (int kk = 0; kk < 4; kk++) {
            float4 b = *(float4*)(Wl + (64 + k4 + kk) * 64 + f0);
            #pragma unroll
            for (int i = 0; i < 4; i++) {
                float av = (&a[i].x)[kk];
                acc[i][0] = fmaf(av, b.x, acc[i][0]);
                acc[i][1] = fmaf(av, b.y, acc[i][1]);
                acc[i][2] = fmaf(av, b.z, acc[i][2]);
                acc[i][3] = fmaf(av, b.w, acc[i][3]);
            }
        }
    }
    __syncthreads();
    // write gated (bf16, global) + stash fp32 tile in As for stats
    #pragma unroll
    for (int i = 0; i < 4; i++) {
        int e = ty + 16 * i, ge = e0 + e;
        unsigned long long pk =
            (unsigned long long)f2bf(acc[i][0])
          | ((unsigned long long)f2bf(acc[i][1]) << 16)
          | ((unsigned long long)f2bf(acc[i][2]) << 32)
          | ((unsigned long long)f2bf(acc[i][3]) << 48);
        *(unsigned long long*)(gated + (size_t)ge * 128 + half * 64 + f0) = pk;
        *(float4*)(As + e * SA + f0) = make_float4(acc[i][0], acc[i][1], acc[i][2], acc[i][3]);
    }
    __syncthreads();

    // stats over the 64-edge tile, features half*64 + [0,64)
    const int fl = t & 63, g = t >> 6;       // g = wave id, scans 16 edges
    const bool pure = (cl[0] == cl[TE - 1]); // sorted => whole block one crystal
    float s = 0.f, q2 = 0.f;
    if (pure) {
        #pragma unroll 4
        for (int e = g * 16; e < g * 16 + 16; e++) {
            float v = As[e * SA + fl];
            s += v; q2 += v * v;
        }
        ptS[g][fl] = s; ptQ[g][fl] = q2;
        __syncthreads();
        if (t < 64) {
            float S = ptS[0][t] + ptS[1][t] + ptS[2][t] + ptS[3][t];
            float Q = ptQ[0][t] + ptQ[1][t] + ptQ[2][t] + ptQ[3][t];
            int c = cl[0];
            atomicAdd(&sum1[c * 128 + half * 64 + t], S);
            atomicAdd(&sq1 [c * 128 + half * 64 + t], Q);
        }
    } else {
        int cp = cl[g * 16];
        for (int e = g * 16; e < g * 16 + 16; e++) {
            int cc = cl[e];
            if (cc != cp) {
                atomicAdd(&sum1[cp * 128 + half * 64 + fl], s);
                atomicAdd(&sq1 [cp * 128 + half * 64 + fl], q2);
                s = 0.f; q2 = 0.f; cp = cc;
            }
            float v = As[e * SA + fl];
            s += v; q2 += v * v;
        }
        atomicAdd(&sum1[cp * 128 + half * 64 + fl], s);
        atomicAdd(&sq1 [cp * 128 + half * 64 + fl], q2);
    }
}

// ---------- K2: normalize1 + tanh gate -> mid, + stats2 ----------
// wave per edge (lane = feature), 4 waves/block, 64 edges per wave
__global__ __launch_bounds__(256) void k_gate(
    const unsigned short* __restrict__ gated, const int* __restrict__ cidx,
    const float* __restrict__ sum1, const float* __restrict__ sq1,
    const float* __restrict__ cntb,
    const float* __restrict__ gamma1, const float* __restrict__ beta1,
    const float* __restrict__ Wm,
    unsigned short* __restrict__ mid,
    float* __restrict__ sum2, float* __restrict__ sq2)
{
    const int w = threadIdx.x >> 6, f = threadIdx.x & 63;
    const int base = blockIdx.x * 256 + w * 64;
    const float g1c = gamma1[f], b1c = beta1[f];
    const float g1f = gamma1[64 + f], b1f = beta1[64 + f];
    const float wm = Wm[f];

    int cprev = -1, crun = -1;
    float m_c = 0.f, r_c = 0.f, m_f = 0.f, r_f = 0.f;
    float s_acc = 0.f, q_acc = 0.f;

    for (int it = 0; it < 64; it++) {
        int e = base + it;
        if (e >= E_EDGES) break;
        int c = cidx[e];                 // wave-uniform
        if (c != cprev) {
            float rc = 1.f / fmaxf(cntb[c], 1.f);
            float m1 = sum1[c * 128 + f] * rc;
            float v1 = sq1[c * 128 + f] * rc - m1 * m1;
            m_c = m1; r_c = rsqrtf(v1 + EPS_C);
            float m2 = sum1[c * 128 + 64 + f] * rc;
            float v2 = sq1[c * 128 + 64 + f] * rc - m2 * m2;
            m_f = m2; r_f = rsqrtf(v2 + EPS_C);
            cprev = c;
        }
        float core = bf2f(gated[(size_t)e * 128 + f]);
        float filt = bf2f(gated[(size_t)e * 128 + 64 + f]);
        float cn = (core - m_c) * r_c * g1c + b1c;
        float fn = (filt - m_f) * r_f * g1f + b1f;
        float p = fn * wm;
        #pragma unroll
        for (int o = 32; o > 0; o >>= 1) p += __shfl_xor(p, o, 64);
        float th = tanhf(p);
        float v = th * fmaxf(cn, 0.f);
        mid[(size_t)e * 64 + f] = f2bf(v);
        if (c != crun) {
            if (crun >= 0) {
                atomicAdd(&sum2[crun * 64 + f], s_acc);
                atomicAdd(&sq2 [crun * 64 + f], q_acc);
            }
            s_acc = 0.f; q_acc = 0.f; crun = c;
        }
        s_acc += v; q_acc += v * v;
    }
    if (crun >= 0) {
        atomicAdd(&sum2[crun * 64 + f], s_acc);
        atomicAdd(&sq2 [crun * 64 + f], q_acc);
    }
}

// ---------- K3: normalize2 + 2 residual MLPs + final relu ----------
// thread per edge; x[64],h[32] in VGPRs; weights wave-uniform -> scalar loads
__global__ __launch_bounds__(256) void k_mlp(
    const unsigned short* __restrict__ mid, const int* __restrict__ cidx,
    const float* __restrict__ edg,
    const float* __restrict__ sum2, const float* __restrict__ sq2,
    const float* __restrict__ cntb,
    const float* __restrict__ gamma2, const float* __restrict__ beta2,
    const float* __restrict__ rW1, const float* __restrict__ rB1,
    const float* __restrict__ rW2, const float* __restrict__ rB2,
    float* __restrict__ out)
{
    int e = blockIdx.x * 256 + threadIdx.x;
    if (e >= E_EDGES) return;
    int c = cidx[e];
    float rc = 1.f / fmaxf(cntb[c], 1.f);

    float x[64];
    const unsigned short* mrow = mid + (size_t)e * 64;
    #pragma unroll
    for (int q = 0; q < 16; q++) {
        unsigned long long u = *(const unsigned long long*)(mrow + q * 4);
        #pragma unroll
        for (int j = 0; j < 4; j++) {
            int f = q * 4 + j;
            float xv = bf2f((unsigned short)(u >> (16 * j)));
            float m = sum2[c * 64 + f] * rc;
            float vv = sq2[c * 64 + f] * rc - m * m;
            x[f] = (xv - m) * rsqrtf(vv + EPS_C) * gamma2[f] + beta2[f];
        }
    }
    #pragma unroll
    for (int i = 0; i < 2; i++) {
        float h[32];
        #pragma unroll
        for (int j = 0; j < 32; j++) h[j] = rB1[i * 32 + j];
        #pragma unroll
        for (int f = 0; f < 64; f++) {
            const float* wrow = rW1 + i * 2048 + f * 32;   // uniform -> s_load
            float xv = x[f];
            #pragma unroll
            for (int j = 0; j < 32; j++) h[j] = fmaf(xv, wrow[j], h[j]);
        }
        #pragma unroll
        for (int j = 0; j < 32; j++) h[j] = fmaxf(h[j], 0.f);
        #pragma unroll
        for (int f = 0; f < 64; f++) x[f] += rB2[i * 64 + f];
        #pragma unroll
        for (int j = 0; j < 32; j++) {
            const float* wrow = rW2 + i * 2048 + j * 64;   // uniform -> s_load
            float hv = h[j];
            #pragma unroll
            for (int f = 0; f < 64; f++) x[f] = fmaf(hv, wrow[f], x[f]);
        }
    }
    const float* erow = edg + (size_t)e * 64;
    float* orow = out + (size_t)e * 64;
    #pragma unroll
    for (int q = 0; q < 16; q++) {
        float4 ev = *(const float4*)(erow + q * 4);
        float4 o;
        o.x = INV_SQRT2 * fmaxf(ev.x + x[q * 4 + 0], 0.f);
        o.y = INV_SQRT2 * fmaxf(ev.y + x[q * 4 + 1], 0.f);
        o.z = INV_SQRT2 * fmaxf(ev.z + x[q * 4 + 2], 0.f);
        o.w = INV_SQRT2 * fmaxf(ev.w + x[q * 4 + 3], 0.f);
        *(float4*)(orow + q * 4) = o;
    }
}

extern "C" void kernel_launch(void* const* d_in, const int* in_sizes, int n_in,
                              void* d_out, int out_size, void* d_ws, size_t ws_size,
                              hipStream_t stream)
{
    const float* atom   = (const float*)d_in[0];
    const float* edg    = (const float*)d_in[1];
    const int*   nbr    = (const int*)d_in[2];
    const int*   cidx   = (const int*)d_in[3];
    const float* Wf     = (const float*)d_in[4];
    const float* Wm     = (const float*)d_in[5];
    const float* gamma1 = (const float*)d_in[6];
    const float* beta1  = (const float*)d_in[7];
    const float* gamma2 = (const float*)d_in[8];
    const float* beta2  = (const float*)d_in[9];
    const float* rW1    = (const float*)d_in[10];
    const float* rB1    = (const float*)d_in[11];
    const float* rW2    = (const float*)d_in[12];
    const float* rB2    = (const float*)d_in[13];
    float* out = (float*)d_out;

    char* ws = (char*)d_ws;
    unsigned short* gated = (unsigned short*)ws;                              // E*128 bf16
    unsigned short* mid   = (unsigned short*)(ws + (size_t)E_EDGES * 128 * 2); // E*64 bf16
    float* stats = (float*)(ws + (size_t)E_EDGES * 128 * 2 + (size_t)E_EDGES * 64 * 2);
    float* sum1 = stats;                 // 256*128
    float* sq1  = sum1 + 256 * 128;      // 256*128
    float* sum2 = sq1 + 256 * 128;       // 256*64
    float* sq2  = sum2 + 256 * 64;       // 256*64
    float* cntb = sq2 + 256 * 64;        // 256

    const int nstat = 2 * 256 * 128 + 2 * 256 * 64;
    k_zero<<<(nstat + 255) / 256, 256, 0, stream>>>(sum1, nstat);
    k_bounds<<<1, 256, 0, stream>>>(cidx, cntb);
    k_gemm1<<<(E_EDGES / TE) * 2, 256, 0, stream>>>(atom, edg, nbr, cidx, Wf, gated, sum1, sq1);
    k_gate<<<(E_EDGES + 255) / 256, 256, 0, stream>>>(gated, cidx, sum1, sq1, cntb,
                                                      gamma1, beta1, Wm, mid, sum2, sq2);
    k_mlp<<<(E_EDGES + 255) / 256, 256, 0, stream>>>(mid, cidx, edg, sum2, sq2, cntb,
                                                     gamma2, beta2, rW1, rB1, rW2, rB2, out);
}